// Round 6
// baseline (308.427 us; speedup 1.0000x reference)
//
#include <hip/hip_runtime.h>
#include <hip/hip_bf16.h>
#include <cstddef>
#include <cstdint>

#define B_SZ   8
#define T_CTX  1024
#define C_DIM  1024
#define H_NUM  16
#define HS     64
#define M_ROWS (B_SZ * T_CTX)

typedef __attribute__((ext_vector_type(8))) short bf16x8;
typedef __attribute__((ext_vector_type(8))) unsigned short u16x8;
typedef __attribute__((ext_vector_type(4))) float f32x4;

static __device__ inline unsigned short f2bf(float f) {
    __hip_bfloat16 h = __float2bfloat16(f);
    return __builtin_bit_cast(unsigned short, h);
}
static __device__ inline float bf2f(unsigned short u) {
    unsigned int v = ((unsigned int)u) << 16;
    return __builtin_bit_cast(float, v);
}
static __device__ inline void gld16(const void* g, void* l) {
    __builtin_amdgcn_global_load_lds((const __attribute__((address_space(1))) void*)g,
                                     (__attribute__((address_space(3))) void*)l,
                                     16, 0, 0);
}

// ---------------------------------------------------------------------------
// Fused conversion: blocks [0,8192) do x->xs (bf16, time-shifted);
// blocks [8192,12288) do the 4 weight matrices -> stacked bf16.
// ---------------------------------------------------------------------------
__global__ __launch_bounds__(256)
void convert_all(const float* __restrict__ x, unsigned short* __restrict__ xs,
                 const float* __restrict__ Wk, const float* __restrict__ Wv,
                 const float* __restrict__ Wr, const float* __restrict__ Wo,
                 unsigned short* __restrict__ wdst)
{
    const int bid = blockIdx.x;
    if (bid < 8192) {
        const int idx = (bid * 256 + threadIdx.x) * 4;
        const int m = idx >> 10;
        const int c = idx & 1023;
        float4 v;
        if (c < 512) {
            const int t = m & (T_CTX - 1);
            if (t == 0) v = make_float4(0.f, 0.f, 0.f, 0.f);
            else        v = *(const float4*)(x + (size_t)(m - 1) * C_DIM + c);
        } else {
            v = *(const float4*)(x + idx);
        }
        ushort4 o;
        o.x = f2bf(v.x); o.y = f2bf(v.y); o.z = f2bf(v.z); o.w = f2bf(v.w);
        *(ushort4*)(xs + idx) = o;
    } else {
        const int wid = bid - 8192;
        const int z = wid >> 10;
        const float* src = (z == 0) ? Wk : (z == 1) ? Wv : (z == 2) ? Wr : Wo;
        const int idx = ((wid & 1023) * 256 + threadIdx.x) * 4;
        const float4 v = *(const float4*)(src + idx);
        ushort4 o;
        o.x = f2bf(v.x); o.y = f2bf(v.y); o.z = f2bf(v.z); o.w = f2bf(v.w);
        *(ushort4*)(wdst + (size_t)z * (C_DIM * C_DIM) + idx) = o;
    }
}

// ---------------------------------------------------------------------------
// bf16 MFMA GEMM, BM=256 BN=128 BK=64, wave tile 128x64 (acc 8x4), XOR LDS
// swizzle (slot = chunk ^ (row&7)) -> conflict-free b128 fragment reads with
// 1.33x fewer LDS reads per MFMA than the 64x64 wave tile (LDS-BW bound).
// multi=1: W stacked [3072x1024]; mode = n0>>10:
//   0: exp(clip)->fp32 expk ; 1: identity->bf16 v ; 2: sigmoid->bf16 sigr
// multi=0: mode 3: (v+bias)*gamma[t] -> fp32 out
// Block swizzle: d%8 = XCD gets 4 consecutive M-bands (2MB A set, L2-local):
//   y = ((d&7)<<2)|((d>>3)&3), xb = d>>5.
// ---------------------------------------------------------------------------
__global__ __launch_bounds__(256, 2)
void mfma_gemm256(const unsigned short* __restrict__ A,
                  const unsigned short* __restrict__ Wb,
                  const float* __restrict__ b0, const float* __restrict__ b1,
                  const float* __restrict__ b2,
                  void* __restrict__ o0, void* __restrict__ o1, void* __restrict__ o2,
                  const float* __restrict__ gamma, int multi)
{
    const int d  = blockIdx.x;
    const int y  = ((d & 7) << 2) | ((d >> 3) & 3);
    const int xb = d >> 5;
    const int m0 = y * 256, n0 = xb * 128;

    int mode, ncol0;
    const float* bias;
    void* out;
    if (multi) {
        const int z = n0 >> 10;
        mode = z;
        ncol0 = n0 & 1023;
        bias = (z == 0) ? b0 : (z == 1) ? b1 : b2;
        out  = (z == 0) ? o0 : (z == 1) ? o1 : o2;
    } else {
        mode = 3; ncol0 = n0; bias = b0; out = o0;
    }

    __shared__ unsigned short As[256 * 64];   // 32 KB
    __shared__ unsigned short Bs[128 * 64];   // 16 KB

    const int tid = threadIdx.x;
    const int w = tid >> 6, l = tid & 63;

    // staging: lane l -> row offset r8=l>>3, fetches global chunk (l&7)^r8 so
    // row R slot s holds chunk s^(R&7)  (gld16 writes stay contiguous).
    const int r8  = l >> 3;
    const int c16 = ((l & 7) ^ r8) * 8;
    const unsigned short* gA = A  + (size_t)(m0 + w * 64 + r8) * C_DIM + c16;
    const unsigned short* gB = Wb + (size_t)(n0 + w * 32 + r8) * C_DIM + c16;
    char* lA = (char*)As + (w * 64) * 128;
    char* lB = (char*)Bs + (w * 32) * 128;

    const int wr = w >> 1, wc = w & 1;       // wr: M-half(128), wc: N-half(64)
    const int lr = l & 15, lkq = l >> 4;
    const int x7 = lr & 7;

    f32x4 acc[8][4];
    #pragma unroll
    for (int i = 0; i < 8; ++i)
        #pragma unroll
        for (int j = 0; j < 4; ++j) acc[i][j] = (f32x4){0.f, 0.f, 0.f, 0.f};

    for (int k0 = 0; k0 < C_DIM; k0 += 64) {
        #pragma unroll
        for (int r = 0; r < 8; ++r)
            gld16(gA + k0 + (size_t)r * 8 * C_DIM, lA + r * 8 * 128);
        #pragma unroll
        for (int r = 0; r < 4; ++r)
            gld16(gB + k0 + (size_t)r * 8 * C_DIM, lB + r * 8 * 128);
        __syncthreads();

        #pragma unroll
        for (int ks = 0; ks < 2; ++ks) {
            const int slot = ((ks * 4 + lkq) ^ x7) * 8;
            bf16x8 af[8], bfv[4];
            #pragma unroll
            for (int i = 0; i < 8; ++i)
                af[i] = *(const bf16x8*)&As[(wr * 128 + i * 16 + lr) * 64 + slot];
            #pragma unroll
            for (int j = 0; j < 4; ++j)
                bfv[j] = *(const bf16x8*)&Bs[(wc * 64 + j * 16 + lr) * 64 + slot];
            #pragma unroll
            for (int i = 0; i < 8; ++i)
                #pragma unroll
                for (int j = 0; j < 4; ++j)
                    acc[i][j] = __builtin_amdgcn_mfma_f32_16x16x32_bf16(
                        af[i], bfv[j], acc[i][j], 0, 0, 0);
        }
        __syncthreads();
    }

    // epilogue: C/D layout col=lane&15, row=(lane>>4)*4+reg
    #pragma unroll
    for (int j = 0; j < 4; ++j) {
        const int col = ncol0 + wc * 64 + j * 16 + lr;
        const float bz = bias[col];
        #pragma unroll
        for (int i = 0; i < 8; ++i) {
            const int rb = m0 + wr * 128 + i * 16 + lkq * 4;
            #pragma unroll
            for (int r = 0; r < 4; ++r) {
                const int row = rb + r;
                float v = acc[i][j][r] + bz;
                if (mode == 0)      v = __expf(fminf(fmaxf(v, -60.f), 30.f));
                else if (mode == 2) v = 1.f / (1.f + __expf(-v));
                else if (mode == 3) v *= gamma[row & (T_CTX - 1)];
                if (mode == 1 || mode == 2)
                    ((unsigned short*)out)[(size_t)row * C_DIM + col] = f2bf(v);
                else
                    ((float*)out)[(size_t)row * C_DIM + col] = v;
            }
        }
    }
}

// ---------------------------------------------------------------------------
// Chunk-local cumsum of expk (64-row chunks, 512 blocks = 2/CU) +
// kvT[b,h,c,u] = bf16(expk * v * alpha[h,u]).
// sumk holds CHUNK-LOCAL prefix sums; aux[b,q,n] (q=0..15) = raw chunk totals
// (prefix-summed on the fly in the wkv epilogue).
// ---------------------------------------------------------------------------
__global__ __launch_bounds__(256)
void cumsum_chunk(const float* __restrict__ expk, const unsigned short* __restrict__ vbf,
                  const float* __restrict__ alpha,
                  float* __restrict__ sumk, unsigned short* __restrict__ kvT,
                  float* __restrict__ aux)
{
    const int n = blockIdx.x * 256 + threadIdx.x;
    const int q = blockIdx.y;                 // 64-row chunk
    const int b = blockIdx.z;
    const int h = n >> 6, c = n & 63;
    const size_t base = ((size_t)b * T_CTX + q * 64) * C_DIM + n;
    unsigned short* kvrow = kvT + (((size_t)b * H_NUM + h) * HS + c) * T_CTX + q * 64;
    float s = 0.f;
    u16x8 buf;
    #pragma unroll 8
    for (int i = 0; i < 64; ++i) {
        const size_t idx = base + (size_t)i * C_DIM;
        const float e  = expk[idx];
        const float vv = bf2f(vbf[idx]);
        const float a  = alpha[h * T_CTX + q * 64 + i];
        s += e;
        sumk[idx] = s;
        buf[i & 7] = f2bf(e * vv * a);
        if ((i & 7) == 7) *(u16x8*)(kvrow + i - 7) = buf;
    }
    aux[((size_t)b * 16 + q) * C_DIM + n] = s;
}

// ---------------------------------------------------------------------------
// wkv via MFMA (Toeplitz):  wkv[t,c] = sum_u twx[1023-t+u] * kvT[c,u]
// A-frags from 8 shift-replicas of twx in LDS; B = kvT tile in padded LDS.
// Epilogue: rwkv = sigr * beta[t] * acc / (sumk_chunk + prefix(aux))  (bf16)
// Block covers t-chunks 2*bx and 2*bx+1 (64-row chunks).
// ---------------------------------------------------------------------------
#define REPL_STRIDE 1176
#define REPL_USED   1168

__global__ __launch_bounds__(256)
void wkv_mfma(const unsigned short* __restrict__ kvT,
              const float* __restrict__ sumk,
              const unsigned short* __restrict__ sigr,
              const float* __restrict__ tw, const float* __restrict__ beta,
              const float* __restrict__ aux,
              unsigned short* __restrict__ rwkv)
{
    __shared__ unsigned short repl[8 * REPL_STRIDE];
    __shared__ unsigned short kv_s[64 * 72];
    __shared__ unsigned short tw_s[1024];

    const int tid = threadIdx.x;
    const int bx = blockIdx.x;
    const int t0 = bx * 128;
    const int h  = blockIdx.y;
    const int b  = blockIdx.z;

    {
        const int i = tid * 4;
        const float4 v = *(const float4*)(tw + h * T_CTX + i);
        ushort4 o;
        o.x = f2bf(v.x); o.y = f2bf(v.y); o.z = f2bf(v.z); o.w = f2bf(v.w);
        *(ushort4*)&tw_s[i] = o;
    }
    __syncthreads();

    #pragma unroll
    for (int r = 0; r < 8; ++r)
        for (int i = tid; i < REPL_USED; i += 256) {
            const int src = i + r;
            repl[r * REPL_STRIDE + i] = (src < 1024) ? tw_s[src] : (unsigned short)0;
        }
    __syncthreads();

    const int w = tid >> 6, l = tid & 63;
    const int wr = w >> 1, wc = w & 1;
    const int lr = l & 15, lkq = l >> 4;

    const int r    = (7 - lr) & 7;
    const int S0   = 1023 - t0 - wr * 64 - lr + lkq * 8;
    const int abase = 2 * S0 + (2 * REPL_STRIDE - 2) * r;
    const char* repl_c = (const char*)repl;

    const int srow = tid >> 2;
    const int ucol = (tid & 3) * 16;
    const unsigned short* gkv = kvT + (((size_t)b * H_NUM + h) * HS + srow) * T_CTX + ucol;
    unsigned short* skv = &kv_s[srow * 72 + ucol];

    f32x4 acc[4][2];
    #pragma unroll
    for (int i = 0; i < 4; ++i) {
        acc[i][0] = (f32x4){0.f, 0.f, 0.f, 0.f};
        acc[i][1] = (f32x4){0.f, 0.f, 0.f, 0.f};
    }

    const int nsteps = t0 / 64 + 2;
    for (int ks = 0; ks < nsteps; ++ks) {
        const int u0 = ks * 64;
        const u16x8 q0 = *(const u16x8*)(gkv + u0);
        const u16x8 q1 = *(const u16x8*)(gkv + u0 + 8);
        __syncthreads();
        *(u16x8*)skv       = q0;
        *(u16x8*)(skv + 8) = q1;
        __syncthreads();

        const int ub = abase + 2 * u0;
        #pragma unroll
        for (int kk = 0; kk < 2; ++kk) {
            bf16x8 af[4], bfv[2];
            #pragma unroll
            for (int i = 0; i < 4; ++i)
                af[i] = *(const bf16x8*)(repl_c + (ub + kk * 64 - i * 32));
            #pragma unroll
            for (int j = 0; j < 2; ++j)
                bfv[j] = *(const bf16x8*)&kv_s[(wc * 32 + j * 16 + lr) * 72 + kk * 32 + lkq * 8];
            #pragma unroll
            for (int i = 0; i < 4; ++i)
                #pragma unroll
                for (int j = 0; j < 2; ++j)
                    acc[i][j] = __builtin_amdgcn_mfma_f32_16x16x32_bf16(
                        af[i], bfv[j], acc[i][j], 0, 0, 0);
        }
    }

    // aux prefixes: block spans 64-row chunks 2bx (lower) and 2bx+1 (upper)
    float off0[2], off1[2];
    #pragma unroll
    for (int j = 0; j < 2; ++j) {
        const int cl = wc * 32 + j * 16 + lr;
        float o = 0.f;
        for (int q = 0; q < 2 * bx; ++q)
            o += aux[((size_t)b * 16 + q) * C_DIM + h * HS + cl];
        off0[j] = o;
        off1[j] = o + aux[((size_t)b * 16 + 2 * bx) * C_DIM + h * HS + cl];
    }

    #pragma unroll
    for (int i = 0; i < 4; ++i) {
        const int tb = t0 + wr * 64 + i * 16 + lkq * 4;
        #pragma unroll
        for (int rg = 0; rg < 4; ++rg) {
            const int t = tb + rg;
            const int hi = (t >> 6) & 1;
            const float bet = beta[h * T_CTX + t];
            const size_t row_off = ((size_t)(b * T_CTX + t)) * C_DIM + h * HS;
            #pragma unroll
            for (int j = 0; j < 2; ++j) {
                const int cl = wc * 32 + j * 16 + lr;
                const float sk = sumk[row_off + cl] + (hi ? off1[j] : off0[j]);
                const float sr = bf2f(sigr[row_off + cl]);
                rwkv[row_off + cl] = f2bf(sr * bet * acc[i][j][rg] / sk);
            }
        }
    }
}

// ---------------------------------------------------------------------------
extern "C" void kernel_launch(void* const* d_in, const int* in_sizes, int n_in,
                              void* d_out, int out_size, void* d_ws, size_t ws_size,
                              hipStream_t stream)
{
    const float* x     = (const float*)d_in[0];
    const float* tw    = (const float*)d_in[1];
    const float* alpha = (const float*)d_in[2];
    const float* beta  = (const float*)d_in[3];
    const float* gamma = (const float*)d_in[4];
    const float* Wk    = (const float*)d_in[5];
    const float* bk    = (const float*)d_in[6];
    const float* Wv    = (const float*)d_in[7];
    const float* bv    = (const float*)d_in[8];
    const float* Wr    = (const float*)d_in[9];
    const float* br    = (const float*)d_in[10];
    const float* Wo    = (const float*)d_in[11];
    const float* bo    = (const float*)d_in[12];
    float* out = (float*)d_out;

    // workspace layout (bytes), max 128M:
    //  [0,32M)   expk fp32    -> rwkv bf16 [0,16M) after cumsum
    //  [32,48M)  v bf16
    //  [48,56M)  weights bf16 (Wk,Wv,Wr,Wo stacked @ 2MB each)
    //  [56,56.5M) aux (raw 64-chunk totals, 16 per b)
    //  [64,96M)  sumk fp32 (chunk-local)  (xs bf16 overlays [64,80M) during proj)
    //  [96,112M) sigr bf16
    //  [112,128M) kvT bf16
    char* W = (char*)d_ws;
    float* expk          = (float*)W;
    unsigned short* rwkv = (unsigned short*)W;
    unsigned short* vbf  = (unsigned short*)(W + (32ull << 20));
    unsigned short* wbf  = (unsigned short*)(W + (48ull << 20));
    float* aux           = (float*)(W + (56ull << 20));
    float* sumk          = (float*)(W + (64ull << 20));
    unsigned short* xs   = (unsigned short*)(W + (64ull << 20));
    unsigned short* sigr = (unsigned short*)(W + (96ull << 20));
    unsigned short* kvT  = (unsigned short*)(W + (112ull << 20));

    const size_t WSZ = (size_t)C_DIM * C_DIM;

    convert_all<<<dim3(12288), 256, 0, stream>>>(x, xs, Wk, Wv, Wr, Wo, wbf);

    // k,v,r projections as one N=3072 GEMM (W stacked), XCD-swizzled
    mfma_gemm256<<<dim3(768), 256, 0, stream>>>(
        xs, wbf, bk, bv, br, expk, vbf, sigr, gamma, 1);

    cumsum_chunk<<<dim3(4, 16, 8), 256, 0, stream>>>(expk, vbf, alpha, sumk, kvT, aux);

    wkv_mfma<<<dim3(8, 16, 8), 256, 0, stream>>>(
        kvT, sumk, sigr, tw, beta, aux, rwkv);

    // output projection + gamma
    mfma_gemm256<<<dim3(256), 256, 0, stream>>>(
        rwkv, wbf + 3 * WSZ, bo, nullptr, nullptr,
        out, nullptr, nullptr, gamma, 0);
}

// Round 7
// 286.779 us; speedup vs baseline: 1.0755x; 1.0755x over previous
//
#include <hip/hip_runtime.h>
#include <hip/hip_bf16.h>
#include <cstddef>
#include <cstdint>

#define B_SZ   8
#define T_CTX  1024
#define C_DIM  1024
#define H_NUM  16
#define HS     64
#define M_ROWS (B_SZ * T_CTX)

typedef __attribute__((ext_vector_type(8))) short bf16x8;
typedef __attribute__((ext_vector_type(8))) unsigned short u16x8;
typedef __attribute__((ext_vector_type(4))) float f32x4;

static __device__ inline unsigned short f2bf(float f) {
    __hip_bfloat16 h = __float2bfloat16(f);
    return __builtin_bit_cast(unsigned short, h);
}
static __device__ inline float bf2f(unsigned short u) {
    unsigned int v = ((unsigned int)u) << 16;
    return __builtin_bit_cast(float, v);
}
static __device__ inline void gld16(const void* g, void* l) {
    __builtin_amdgcn_global_load_lds((const __attribute__((address_space(1))) void*)g,
                                     (__attribute__((address_space(3))) void*)l,
                                     16, 0, 0);
}

// ---------------------------------------------------------------------------
// Fused conversion: blocks [0,8192) do x->xs (bf16, time-shifted);
// blocks [8192,12288) do the 4 weight matrices -> stacked bf16.
// ---------------------------------------------------------------------------
__global__ __launch_bounds__(256)
void convert_all(const float* __restrict__ x, unsigned short* __restrict__ xs,
                 const float* __restrict__ Wk, const float* __restrict__ Wv,
                 const float* __restrict__ Wr, const float* __restrict__ Wo,
                 unsigned short* __restrict__ wdst)
{
    const int bid = blockIdx.x;
    if (bid < 8192) {
        const int idx = (bid * 256 + threadIdx.x) * 4;
        const int m = idx >> 10;
        const int c = idx & 1023;
        float4 v;
        if (c < 512) {
            const int t = m & (T_CTX - 1);
            if (t == 0) v = make_float4(0.f, 0.f, 0.f, 0.f);
            else        v = *(const float4*)(x + (size_t)(m - 1) * C_DIM + c);
        } else {
            v = *(const float4*)(x + idx);
        }
        ushort4 o;
        o.x = f2bf(v.x); o.y = f2bf(v.y); o.z = f2bf(v.z); o.w = f2bf(v.w);
        *(ushort4*)(xs + idx) = o;
    } else {
        const int wid = bid - 8192;
        const int z = wid >> 10;
        const float* src = (z == 0) ? Wk : (z == 1) ? Wv : (z == 2) ? Wr : Wo;
        const int idx = ((wid & 1023) * 256 + threadIdx.x) * 4;
        const float4 v = *(const float4*)(src + idx);
        ushort4 o;
        o.x = f2bf(v.x); o.y = f2bf(v.y); o.z = f2bf(v.z); o.w = f2bf(v.w);
        *(ushort4*)(wdst + (size_t)z * (C_DIM * C_DIM) + idx) = o;
    }
}

// ---------------------------------------------------------------------------
// bf16 MFMA GEMM, 128x128 tile, BK=64, XOR-swizzled LDS (slot = chunk^(row&7))
// -> conflict-free b128 fragment reads.  (R5 config: the proven 74 us / 28%
// MfmaUtil point; 256x128 wave-tiling regressed via register pressure.)
// multi=1: W stacked [3072x1024]; mode = n0>>10:
//   0: exp(clip)->fp32 expk ; 1: identity->bf16 v ; 2: sigmoid->bf16 sigr
// multi=0: mode 3: (v+bias)*gamma[t] -> fp32 out
// Block swizzle: d -> y=((d&7)<<3)|((d>>3)&7), x=d>>6 (XCD L2 locality).
// ---------------------------------------------------------------------------
__global__ __launch_bounds__(256, 2)
void mfma_gemm64(const unsigned short* __restrict__ A,
                 const unsigned short* __restrict__ Wb,
                 const float* __restrict__ b0, const float* __restrict__ b1,
                 const float* __restrict__ b2,
                 void* __restrict__ o0, void* __restrict__ o1, void* __restrict__ o2,
                 const float* __restrict__ gamma, int multi)
{
    const int d  = blockIdx.x;
    const int y  = ((d & 7) << 3) | ((d >> 3) & 7);
    const int xb = d >> 6;
    const int m0 = y * 128, n0 = xb * 128;

    int mode, ncol0;
    const float* bias;
    void* out;
    if (multi) {
        const int z = n0 >> 10;
        mode = z;
        ncol0 = n0 & 1023;
        bias = (z == 0) ? b0 : (z == 1) ? b1 : b2;
        out  = (z == 0) ? o0 : (z == 1) ? o1 : o2;
    } else {
        mode = 3; ncol0 = n0; bias = b0; out = o0;
    }

    __shared__ unsigned short As[128 * 64];
    __shared__ unsigned short Bs[128 * 64];

    const int tid = threadIdx.x;
    const int w = tid >> 6, l = tid & 63;

    const int r8  = l >> 3;
    const int c16 = ((l & 7) ^ r8) * 8;
    const unsigned short* gA = A  + (size_t)(m0 + w * 32 + r8) * C_DIM + c16;
    const unsigned short* gB = Wb + (size_t)(n0 + w * 32 + r8) * C_DIM + c16;
    char* lA = (char*)As + (w * 32) * 128;
    char* lB = (char*)Bs + (w * 32) * 128;

    const int wr = w >> 1, wc = w & 1;
    const int lr = l & 15, lkq = l >> 4;
    const int x7 = lr & 7;

    f32x4 acc[4][4];
    #pragma unroll
    for (int i = 0; i < 4; ++i)
        #pragma unroll
        for (int j = 0; j < 4; ++j) acc[i][j] = (f32x4){0.f, 0.f, 0.f, 0.f};

    for (int k0 = 0; k0 < C_DIM; k0 += 64) {
        #pragma unroll
        for (int r = 0; r < 4; ++r) {
            gld16(gA + k0 + (size_t)r * 8 * C_DIM, lA + r * 8 * 128);
            gld16(gB + k0 + (size_t)r * 8 * C_DIM, lB + r * 8 * 128);
        }
        __syncthreads();

        bf16x8 af[2][4], bfv[2][4];
        #pragma unroll
        for (int ks = 0; ks < 2; ++ks) {
            const int slot = ((ks * 4 + lkq) ^ x7) * 8;
            #pragma unroll
            for (int i = 0; i < 4; ++i)
                af[ks][i] = *(const bf16x8*)&As[(wr * 64 + i * 16 + lr) * 64 + slot];
            #pragma unroll
            for (int j = 0; j < 4; ++j)
                bfv[ks][j] = *(const bf16x8*)&Bs[(wc * 64 + j * 16 + lr) * 64 + slot];
        }
        #pragma unroll
        for (int ks = 0; ks < 2; ++ks)
            #pragma unroll
            for (int i = 0; i < 4; ++i)
                #pragma unroll
                for (int j = 0; j < 4; ++j)
                    acc[i][j] = __builtin_amdgcn_mfma_f32_16x16x32_bf16(
                        af[ks][i], bfv[ks][j], acc[i][j], 0, 0, 0);
        __syncthreads();
    }

    #pragma unroll
    for (int j = 0; j < 4; ++j) {
        const int col = ncol0 + wc * 64 + j * 16 + lr;
        const float bz = bias[col];
        #pragma unroll
        for (int i = 0; i < 4; ++i) {
            const int rb = m0 + wr * 64 + i * 16 + lkq * 4;
            #pragma unroll
            for (int r = 0; r < 4; ++r) {
                const int row = rb + r;
                float v = acc[i][j][r] + bz;
                if (mode == 0)      v = __expf(fminf(fmaxf(v, -60.f), 30.f));
                else if (mode == 2) v = 1.f / (1.f + __expf(-v));
                else if (mode == 3) v *= gamma[row & (T_CTX - 1)];
                if (mode == 1 || mode == 2)
                    ((unsigned short*)out)[(size_t)row * C_DIM + col] = f2bf(v);
                else
                    ((float*)out)[(size_t)row * C_DIM + col] = v;
            }
        }
    }
}

// ---------------------------------------------------------------------------
// Chunk-local cumsum of expk (32-row chunks, 1024 blocks = 4/CU) +
// kvT[b,h,c,u] = bf16(expk * v * alpha[h,u]).
// sumk holds CHUNK-LOCAL prefix sums; aux[b,q,n] (q=0..31) = raw chunk totals
// (prefix-summed on the fly in the wkv epilogue).
// ---------------------------------------------------------------------------
__global__ __launch_bounds__(256)
void cumsum_chunk(const float* __restrict__ expk, const unsigned short* __restrict__ vbf,
                  const float* __restrict__ alpha,
                  float* __restrict__ sumk, unsigned short* __restrict__ kvT,
                  float* __restrict__ aux)
{
    const int n = blockIdx.x * 256 + threadIdx.x;
    const int q = blockIdx.y;                 // 32-row chunk
    const int b = blockIdx.z;
    const int h = n >> 6, c = n & 63;
    const size_t base = ((size_t)b * T_CTX + q * 32) * C_DIM + n;
    unsigned short* kvrow = kvT + (((size_t)b * H_NUM + h) * HS + c) * T_CTX + q * 32;
    float s = 0.f;
    u16x8 buf;
    #pragma unroll 8
    for (int i = 0; i < 32; ++i) {
        const size_t idx = base + (size_t)i * C_DIM;
        const float e  = expk[idx];
        const float vv = bf2f(vbf[idx]);
        const float a  = alpha[h * T_CTX + q * 32 + i];
        s += e;
        sumk[idx] = s;
        buf[i & 7] = f2bf(e * vv * a);
        if ((i & 7) == 7) *(u16x8*)(kvrow + i - 7) = buf;
    }
    aux[((size_t)b * 32 + q) * C_DIM + n] = s;
}

// ---------------------------------------------------------------------------
// wkv via MFMA (Toeplitz):  wkv[t,c] = sum_u twx[1023-t+u] * kvT[c,u]
// A-frags from 8 shift-replicas of twx in LDS (alignment: frag base idx ==
// r mod 8 and idx>=0 => slot>=0, max slot 1143 < 1168).
// B = kvT tile 64c x 128u in LDS, 256B rows, XOR-16 slot swizzle
// (slot = chunk ^ (row&15)) -> <=2 lanes/bank-group on b128 reads (free);
// staged via global_load_lds (async DMA), 32 MFMA per barrier pair.
// Epilogue: rwkv = sigr * beta[t] * acc / (sumk_chunk + prefix(aux))  (bf16)
// Block covers 32-row chunks 4bx..4bx+3.
// ---------------------------------------------------------------------------
#define REPL_STRIDE 1176
#define REPL_USED   1168

__global__ __launch_bounds__(256)
void wkv_mfma(const unsigned short* __restrict__ kvT,
              const float* __restrict__ sumk,
              const unsigned short* __restrict__ sigr,
              const float* __restrict__ tw, const float* __restrict__ beta,
              const float* __restrict__ aux,
              unsigned short* __restrict__ rwkv)
{
    __shared__ unsigned short repl[8 * REPL_STRIDE];  // 18816 B
    __shared__ unsigned short kv_s[64 * 128];         // 16 KB
    __shared__ unsigned short tw_s[1024];             // 2 KB

    const int tid = threadIdx.x;
    const int bx = blockIdx.x;
    const int t0 = bx * 128;
    const int h  = blockIdx.y;
    const int b  = blockIdx.z;

    {
        const int i = tid * 4;
        const float4 v = *(const float4*)(tw + h * T_CTX + i);
        ushort4 o;
        o.x = f2bf(v.x); o.y = f2bf(v.y); o.z = f2bf(v.z); o.w = f2bf(v.w);
        *(ushort4*)&tw_s[i] = o;
    }
    __syncthreads();

    #pragma unroll
    for (int r = 0; r < 8; ++r)
        for (int i = tid; i < REPL_USED; i += 256) {
            const int src = i + r;
            repl[r * REPL_STRIDE + i] = (src < 1024) ? tw_s[src] : (unsigned short)0;
        }

    const int w = tid >> 6, l = tid & 63;
    const int wr = w >> 1, wc = w & 1;
    const int lr = l & 15, lkq = l >> 4;

    const int r    = (7 - lr) & 7;
    const int S0   = 1023 - t0 - wr * 64 - lr + lkq * 8;
    const int abase = 2 * S0 + (2 * REPL_STRIDE - 2) * r;
    const char* repl_c = (const char*)repl;

    // kv staging: wave w issue q covers c-rows [q*16 + w*4, +4);
    // lane l -> row q*16 + w*4 + (l>>4), fetches global u-chunk
    // (l&15) ^ (w*4 + (l>>4))  (so row R slot s holds chunk s^(R&15)).
    const int rloc = w * 4 + (l >> 4);
    const int chnk = (l & 15) ^ rloc;
    const unsigned short* gkv =
        kvT + (((size_t)b * H_NUM + h) * HS + rloc) * T_CTX + chnk * 8;
    char* skv = (char*)kv_s + (w * 4) * 256;   // wave-uniform

    f32x4 acc[4][2];
    #pragma unroll
    for (int i = 0; i < 4; ++i) {
        acc[i][0] = (f32x4){0.f, 0.f, 0.f, 0.f};
        acc[i][1] = (f32x4){0.f, 0.f, 0.f, 0.f};
    }
    __syncthreads();   // repl build complete

    const int nsteps = bx + 1;
    for (int ks = 0; ks < nsteps; ++ks) {
        const int u0 = ks * 128;
        #pragma unroll
        for (int q = 0; q < 4; ++q)
            gld16(gkv + (size_t)q * 16 * T_CTX + u0, skv + q * 16 * 256);
        __syncthreads();

        const int ub = abase + 2 * u0;
        #pragma unroll
        for (int kk = 0; kk < 4; ++kk) {
            bf16x8 af[4], bfv[2];
            #pragma unroll
            for (int i = 0; i < 4; ++i)
                af[i] = *(const bf16x8*)(repl_c + (ub + kk * 64 - i * 32));
            #pragma unroll
            for (int j = 0; j < 2; ++j)
                bfv[j] = *(const bf16x8*)&kv_s[(wc * 32 + j * 16 + lr) * 128 +
                                               (((kk * 4 + lkq) ^ lr) * 8)];
            #pragma unroll
            for (int i = 0; i < 4; ++i)
                #pragma unroll
                for (int j = 0; j < 2; ++j)
                    acc[i][j] = __builtin_amdgcn_mfma_f32_16x16x32_bf16(
                        af[i], bfv[j], acc[i][j], 0, 0, 0);
        }
        __syncthreads();
    }

    // aux prefixes: block spans 32-row chunks 4bx..4bx+3
    float off[4][2];
    #pragma unroll
    for (int j = 0; j < 2; ++j) {
        const int cl = wc * 32 + j * 16 + lr;
        float o = 0.f;
        for (int q = 0; q < 4 * bx; ++q)
            o += aux[((size_t)b * 32 + q) * C_DIM + h * HS + cl];
        off[0][j] = o;
        #pragma unroll
        for (int s = 1; s < 4; ++s)
            off[s][j] = off[s - 1][j] +
                aux[((size_t)b * 32 + 4 * bx + s - 1) * C_DIM + h * HS + cl];
    }

    #pragma unroll
    for (int i = 0; i < 4; ++i) {
        const int tb = t0 + wr * 64 + i * 16 + lkq * 4;
        #pragma unroll
        for (int rg = 0; rg < 4; ++rg) {
            const int t = tb + rg;
            const int hi = (t >> 5) & 3;
            const float bet = beta[h * T_CTX + t];
            const size_t row_off = ((size_t)(b * T_CTX + t)) * C_DIM + h * HS;
            #pragma unroll
            for (int j = 0; j < 2; ++j) {
                const int cl = wc * 32 + j * 16 + lr;
                const float sk = sumk[row_off + cl] + off[hi][j];
                const float sr = bf2f(sigr[row_off + cl]);
                rwkv[row_off + cl] = f2bf(sr * bet * acc[i][j][rg] / sk);
            }
        }
    }
}

// ---------------------------------------------------------------------------
extern "C" void kernel_launch(void* const* d_in, const int* in_sizes, int n_in,
                              void* d_out, int out_size, void* d_ws, size_t ws_size,
                              hipStream_t stream)
{
    const float* x     = (const float*)d_in[0];
    const float* tw    = (const float*)d_in[1];
    const float* alpha = (const float*)d_in[2];
    const float* beta  = (const float*)d_in[3];
    const float* gamma = (const float*)d_in[4];
    const float* Wk    = (const float*)d_in[5];
    const float* bk    = (const float*)d_in[6];
    const float* Wv    = (const float*)d_in[7];
    const float* bv    = (const float*)d_in[8];
    const float* Wr    = (const float*)d_in[9];
    const float* br    = (const float*)d_in[10];
    const float* Wo    = (const float*)d_in[11];
    const float* bo    = (const float*)d_in[12];
    float* out = (float*)d_out;

    // workspace layout (bytes), max 128M:
    //  [0,32M)   expk fp32    -> rwkv bf16 [0,16M) after cumsum
    //  [32,48M)  v bf16
    //  [48,56M)  weights bf16 (Wk,Wv,Wr,Wo stacked @ 2MB each)
    //  [56,57M)  aux (raw 32-chunk totals, 32 per b)
    //  [64,96M)  sumk fp32 (chunk-local)  (xs bf16 overlays [64,80M) during proj)
    //  [96,112M) sigr bf16
    //  [112,128M) kvT bf16
    char* W = (char*)d_ws;
    float* expk          = (float*)W;
    unsigned short* rwkv = (unsigned short*)W;
    unsigned short* vbf  = (unsigned short*)(W + (32ull << 20));
    unsigned short* wbf  = (unsigned short*)(W + (48ull << 20));
    float* aux           = (float*)(W + (56ull << 20));
    float* sumk          = (float*)(W + (64ull << 20));
    unsigned short* xs   = (unsigned short*)(W + (64ull << 20));
    unsigned short* sigr = (unsigned short*)(W + (96ull << 20));
    unsigned short* kvT  = (unsigned short*)(W + (112ull << 20));

    const size_t WSZ = (size_t)C_DIM * C_DIM;

    convert_all<<<dim3(12288), 256, 0, stream>>>(x, xs, Wk, Wv, Wr, Wo, wbf);

    // k,v,r projections as one N=3072 GEMM (W stacked), XCD-swizzled
    mfma_gemm64<<<dim3(1536), 256, 0, stream>>>(
        xs, wbf, bk, bv, br, expk, vbf, sigr, gamma, 1);

    cumsum_chunk<<<dim3(4, 32, 8), 256, 0, stream>>>(expk, vbf, alpha, sumk, kvT, aux);

    wkv_mfma<<<dim3(8, 16, 8), 256, 0, stream>>>(
        kvT, sumk, sigr, tw, beta, aux, rwkv);

    // output projection + gamma
    mfma_gemm64<<<dim3(512), 256, 0, stream>>>(
        rwkv, wbf + 3 * WSZ, bo, nullptr, nullptr,
        out, nullptr, nullptr, gamma, 0);
}